// Round 1
// baseline (25.576 us; speedup 1.0000x reference)
//
#include <hip/hip_runtime.h>
#include <math.h>

// Problem constants: B=2, N=512, DIM=3, C_IN=64, C_OUT=64
#define NPT 512
#define NBJ (2 * NPT)   // B*N blocks

// ---------------------------------------------------------------------------
// Kernel A: per (b,j) precompute
//   s[b,j]  = sum_{c<64} sqrt(sum_d geom[b,j,d,c]^2) * norm_w[c] + norm_b
//   Gm[b,j,d,co] = sum_{c<64} geom[b,j,d,c] * theta[c,co]
// ---------------------------------------------------------------------------
__global__ __launch_bounds__(64) void precompute_kernel(
    const float* __restrict__ geom,    // [B,512,3,64]
    const float* __restrict__ theta,   // [65,64]
    const float* __restrict__ norm_w,  // [65]
    const float* __restrict__ norm_b,  // [1]
    float* __restrict__ s,             // [B*512]
    float* __restrict__ gm)            // [B*512,3,64]
{
    const int bj  = blockIdx.x;        // b*512 + j
    const int tid = threadIdx.x;       // 0..63  (= c, and = co)
    __shared__ float g[192];           // geom[b,j,:,:]  layout [d*64 + c]

    const float* gb = geom + (size_t)bj * 192;
    g[tid]       = gb[tid];
    g[tid + 64]  = gb[tid + 64];
    g[tid + 128] = gb[tid + 128];
    __syncthreads();

    // --- s[b,j]: per-channel spatial L2 norm dotted with norm_w ---
    {
        float g0 = g[tid], g1 = g[64 + tid], g2 = g[128 + tid];
        float t = sqrtf(g0 * g0 + g1 * g1 + g2 * g2) * norm_w[tid];
        for (int off = 32; off > 0; off >>= 1) t += __shfl_down(t, off);
        if (tid == 0) s[bj] = t + norm_b[0];
    }

    // --- Gm[b,j,:,co] = geom[b,j,:,:] @ theta[:64,co] ---
    float a0 = 0.f, a1 = 0.f, a2 = 0.f;
    for (int c = 0; c < 64; ++c) {
        float th = theta[c * 64 + tid];           // coalesced across lanes
        a0 = fmaf(g[c],       th, a0);            // LDS broadcast reads
        a1 = fmaf(g[64 + c],  th, a1);
        a2 = fmaf(g[128 + c], th, a2);
    }
    float* gmb = gm + (size_t)bj * 192;
    gmb[tid]       = a0;
    gmb[64 + tid]  = a1;
    gmb[128 + tid] = a2;
}

// ---------------------------------------------------------------------------
// Kernel B: one block per (b,i). 256 threads = 4 waves; lane = co.
//   naf[j] = s[b,j] + norm_w[64]*||rel[b,i,j,:]|| + emb[b,i,j]
//   out[b,i,d,co] = sum_j adj[b,i,j]*relu(alpha[co]*naf[j]+beta[co])
//                         * (Gm[b,j,d,co] + rel[b,i,j,d]*theta[64,co])
// ---------------------------------------------------------------------------
__global__ __launch_bounds__(256) void main_kernel(
    const float* __restrict__ adj,     // [B,512,512]
    const float* __restrict__ rel,     // [B,512,512,3]
    const float* __restrict__ emb,     // [B,512,512]
    const float* __restrict__ theta,   // [65,64]
    const float* __restrict__ norm_w,  // [65]
    const float* __restrict__ alpha,   // [64]
    const float* __restrict__ beta,    // [64]
    const float* __restrict__ s,       // [B*512]
    const float* __restrict__ gm,      // [B*512,3,64]
    float* __restrict__ out)           // [B,512,3,64]
{
    const int bi   = blockIdx.x;       // b*512 + i
    const int b    = bi >> 9;
    const int tid  = threadIdx.x;
    const int lane = tid & 63;         // co
    const int wv   = tid >> 6;         // 0..3

    __shared__ float rel_l[1536];      // [j][d]
    __shared__ float adj_l[512];
    __shared__ float naf_l[512];

    const float* relb = rel + (size_t)bi * 1536;
    const float* adjb = adj + (size_t)bi * 512;
    const float* embb = emb + (size_t)bi * 512;

    for (int k = tid; k < 1536; k += 256) rel_l[k] = relb[k];
    for (int k = tid; k < 512; k += 256) {
        adj_l[k] = adjb[k];
        naf_l[k] = embb[k];            // emb staged; finished below
    }
    __syncthreads();

    const float nw64 = norm_w[64];
    for (int j = tid; j < 512; j += 256) {
        float r0 = rel_l[j * 3], r1 = rel_l[j * 3 + 1], r2 = rel_l[j * 3 + 2];
        naf_l[j] += s[b * 512 + j] + nw64 * sqrtf(r0 * r0 + r1 * r1 + r2 * r2);
    }
    __syncthreads();

    const float al  = alpha[lane];
    const float be  = beta[lane];
    const float t64 = theta[64 * 64 + lane];

    float acc0 = 0.f, acc1 = 0.f, acc2 = 0.f;
    const float* gmb = gm + (size_t)b * (NPT * 192) + lane;
    const int j0 = wv * 128;
    for (int j = j0; j < j0 + 128; ++j) {
        float naf = naf_l[j];                         // LDS broadcast
        float p   = fmaxf(fmaf(al, naf, be), 0.f);
        float wvv = adj_l[j] * p;
        const float* gmj = gmb + j * 192;             // coalesced 256B/d
        float r0 = rel_l[j * 3], r1 = rel_l[j * 3 + 1], r2 = rel_l[j * 3 + 2];
        acc0 = fmaf(wvv, fmaf(r0, t64, gmj[0]),   acc0);
        acc1 = fmaf(wvv, fmaf(r1, t64, gmj[64]),  acc1);
        acc2 = fmaf(wvv, fmaf(r2, t64, gmj[128]), acc2);
    }
    __syncthreads();

    // cross-wave reduction; reuse rel_l as scratch (synced above)
    float* red = rel_l;
    red[wv * 192 + lane]       = acc0;
    red[wv * 192 + 64 + lane]  = acc1;
    red[wv * 192 + 128 + lane] = acc2;
    __syncthreads();
    if (tid < 192) {
        float v = red[tid] + red[192 + tid] + red[384 + tid] + red[576 + tid];
        out[(size_t)bi * 192 + tid] = v;
    }
}

extern "C" void kernel_launch(void* const* d_in, const int* in_sizes, int n_in,
                              void* d_out, int out_size, void* d_ws, size_t ws_size,
                              hipStream_t stream) {
    const float* geom   = (const float*)d_in[0];
    const float* adj    = (const float*)d_in[1];
    const float* rel    = (const float*)d_in[2];
    const float* emb    = (const float*)d_in[3];
    const float* theta  = (const float*)d_in[4];
    const float* norm_w = (const float*)d_in[5];
    const float* norm_b = (const float*)d_in[6];
    const float* alpha  = (const float*)d_in[7];
    const float* beta   = (const float*)d_in[8];
    float* out = (float*)d_out;

    float* s  = (float*)d_ws;          // 1024 floats
    float* gm = s + 1024;              // 196608 floats (total ws ~791 KB)

    precompute_kernel<<<NBJ, 64, 0, stream>>>(geom, theta, norm_w, norm_b, s, gm);
    main_kernel<<<NBJ, 256, 0, stream>>>(adj, rel, emb, theta, norm_w, alpha, beta,
                                         s, gm, out);
}